// Round 4
// baseline (206.669 us; speedup 1.0000x reference)
//
#include <hip/hip_runtime.h>

// NoTradeRegionRNN: D=2, T=512, B=16384.
// One thread per batch column; sequential over T (true data dependence).
// Latency-bound at 1 wave/CU. Key constraint: per-wave vmcnt queue is 63
// entries (hard issue-stall beyond). Pipeline sized to stay under it:
// groups of U=4 steps (16 load entries), 4 rotating slots, prefetch
// distance 3 phases (~900 cy ~= HBM latency), in-flight ~48 loads + few
// store acks < 63. Scalar-base + invariant-voffset addressing.

__global__ __launch_bounds__(64, 1)
void ntr_rnn_kernel(const float* __restrict__ xin,      // (2,T,B)
                    const float* __restrict__ target,   // (2)
                    const float* __restrict__ rets,     // (2,T,B)
                    const float* __restrict__ w_input,  // (2)
                    const float* __restrict__ w_hidden, // (2)
                    const float* __restrict__ b_hidden, // (2)
                    const float* __restrict__ w_fc1,    // (2)
                    const float* __restrict__ w_fc2,    // (2)
                    const float* __restrict__ w_rotate, // (2,2) row-major
                    float* __restrict__ out,            // (2,T,B) then hT (2,B)
                    int T, int B)
{
    const int b = blockIdx.x * blockDim.x + threadIdx.x;
    if (b >= B) return;

    // ---- wave-uniform scalar setup (SGPRs) ----
    const float r00 = w_rotate[0], r01 = w_rotate[1];
    const float r10 = w_rotate[2], r11 = w_rotate[3];
    const float bh0 = b_hidden[0], bh1 = b_hidden[1];
    const float t0  = target[0],   t1  = target[1];

    const float vx[4] = {-bh0, -bh0, bh0, bh0};
    const float vy[4] = {-bh1,  bh1, bh1, -bh1};
    float C[4][2];
#pragma unroll
    for (int c = 0; c < 4; ++c) {
        C[c][0] = r00 * vx[c] + r01 * vy[c] + t0;
        C[c][1] = r10 * vx[c] + r11 * vy[c] + t1;
    }
    const float ac = r10 / r00;
    const float bd = r01 / r11;
    const bool bdp = (bd >= 0.0f);
    const bool acp = (ac >= 0.0f);

    const float cbd_l    = (bdp ? C[0][1] : C[1][1]) * bd;
    const float k_lbx    = fabsf(C[1][0] - C[0][0]);
    const float base_lbx = bdp ? C[1][0] : C[0][0];

    const float cbd_u    = (bdp ? C[3][1] : C[2][1]) * bd;
    const float k_ubx    = fabsf(C[2][0] - C[3][0]);
    const float base_ubx = bdp ? C[2][0] : C[3][0];

    const float cac_l    = (acp ? C[0][0] : C[3][0]) * ac;
    const float k_lby    = fabsf(C[0][1] - C[3][1]);
    const float base_lby = acp ? C[3][1] : C[0][1];

    const float cac_u    = (acp ? C[1][0] : C[2][0]) * ac;
    const float k_uby    = fabsf(C[1][1] - C[2][1]);
    const float base_uby = acp ? C[2][1] : C[1][1];

    const float Wi0 = w_input[0],  Wi1 = w_input[1];
    const float Wh0 = w_hidden[0], Wh1 = w_hidden[1];
    const float W10 = w_fc1[0],    W11 = w_fc1[1];
    const float W20 = w_fc2[0],    W21 = w_fc2[1];

    const size_t TB = (size_t)T * B;
    const float* gx0 = xin;
    const float* gx1 = xin + TB;
    const float* gr0 = rets;
    const float* gr1 = rets + TB;
    float* o0 = out;
    float* o1 = out + TB;

    // h0 = x[:,0,:]
    float hx = gx0[b];
    float hy = gx1[b];
    __builtin_nontemporal_store(hx, &o0[b]);
    __builtin_nontemporal_store(hy, &o1[b]);

    // one recurrence step: h <- cell(x, adjust(h, r))
    auto step = [&](float x0, float x1, float r0, float r1) {
        float denom = fmaf(hx, r0, fmaf(hy, r1, 1.0f));
        float inv   = __builtin_amdgcn_rcpf(denom);      // raw v_rcp_f32
        float nx    = fmaf(hx, r0, hx);                  // hx*(1+r0), off-chain
        float ny    = fmaf(hy, r1, hy);
        float adjx  = nx * inv;
        float adjy  = ny * inv;
        float lbx = base_lbx - fmaxf(k_lbx - fmaxf(fmaf(adjy, bd, -cbd_l), 0.0f), 0.0f);
        float ubx = base_ubx - fmaxf(k_ubx - fmaxf(fmaf(adjy, bd, -cbd_u), 0.0f), 0.0f);
        float lby = base_lby - fmaxf(k_lby - fmaxf(fmaf(adjx, ac, -cac_l), 0.0f), 0.0f);
        float uby = base_uby - fmaxf(k_uby - fmaxf(fmaf(adjx, ac, -cac_u), 0.0f), 0.0f);
        float pre0 = Wi0 * x0;                           // off-chain
        float pre1 = Wi1 * x1;
        float g1x = fmaxf(fmaf(Wh0, adjx, pre0) - lbx, 0.0f);
        float g1y = fmaxf(fmaf(Wh1, adjy, pre1) - lby, 0.0f);
        float g2x = fmaxf(fmaf(W10, g1x, ubx - lbx), 0.0f);
        float g2y = fmaxf(fmaf(W11, g1y, uby - lby), 0.0f);
        hx = fmaf(W20, g2x, ubx);
        hy = fmaf(W21, g2y, uby);
    };

    if (T == 512) {
        // 511 steps = 3 (prologue) + 127 groups of 4. Groups g=0..126 cover
        // t = 4+4g .. 7+4g. 4 slots, prefetch distance 3 phases.
        struct Slot { float x0[4], x1[4], r0[4], r1[4]; };
        Slot S0, S1, S2, S3;

        const size_t B4 = 4 * (size_t)B;

        // running load bases (scalar, advanced per phase); voffsets i*B+b invariant
        const float* lx0 = gx0 + B4;          // x rows start at t=4
        const float* lx1 = gx1 + B4;
        const float* lr0 = gr0 + 3 * (size_t)B;  // r rows start at t-1=3
        const float* lr1 = gr1 + 3 * (size_t)B;
        float* so0 = o0 + B4;                 // store rows start at t=4
        float* so1 = o1 + B4;

#define LOADS(S)                                              \
        do {                                                  \
            _Pragma("unroll")                                 \
            for (int i = 0; i < 4; ++i) {                     \
                S.x0[i] = lx0[i * B + b];                     \
                S.x1[i] = lx1[i * B + b];                     \
                S.r0[i] = lr0[i * B + b];                     \
                S.r1[i] = lr1[i * B + b];                     \
            }                                                 \
            lx0 += B4; lx1 += B4; lr0 += B4; lr1 += B4;       \
        } while (0)

#define COMPS(S)                                              \
        do {                                                  \
            _Pragma("unroll")                                 \
            for (int i = 0; i < 4; ++i) {                     \
                step(S.x0[i], S.x1[i], S.r0[i], S.r1[i]);     \
                __builtin_nontemporal_store(hx, &so0[i * B + b]); \
                __builtin_nontemporal_store(hy, &so1[i * B + b]); \
            }                                                 \
            so0 += B4; so1 += B4;                             \
        } while (0)

        // prologue loads: steps t=1..3 (x at t, r at t-1)
        float Px0[3], Px1[3], Pr0[3], Pr1[3];
#pragma unroll
        for (int i = 0; i < 3; ++i) {
            Px0[i] = gx0[(1 + i) * B + b];
            Px1[i] = gx1[(1 + i) * B + b];
            Pr0[i] = gr0[i * B + b];
            Pr1[i] = gr1[i * B + b];
        }
        LOADS(S0);   // g0 (t=4..7)
        LOADS(S1);   // g1
        LOADS(S2);   // g2

        // prologue compute t=1..3
#pragma unroll
        for (int i = 0; i < 3; ++i) {
            step(Px0[i], Px1[i], Pr0[i], Pr1[i]);
            __builtin_nontemporal_store(hx, &o0[(1 + i) * B + b]);
            __builtin_nontemporal_store(hy, &o1[(1 + i) * B + b]);
        }

        // main: 31 rounds x 4 groups; round r computes g=4r..4r+3,
        // prefetches g=4r+3..4r+6 (r=30 loads g123..g126, the last).
        for (int r = 0; r < 31; ++r) {
            LOADS(S3);  COMPS(S0);
            LOADS(S0);  COMPS(S1);
            LOADS(S1);  COMPS(S2);
            LOADS(S2);  COMPS(S3);
        }
        // tail: g124 (S0), g125 (S1), g126 (S2) already loaded
        COMPS(S0);
        COMPS(S1);
        COMPS(S2);
#undef LOADS
#undef COMPS
    } else {
        // generic fallback (simple, unpipelined)
        for (int t = 1; t < T; ++t) {
            float x0 = gx0[(size_t)t * B + b];
            float x1 = gx1[(size_t)t * B + b];
            float r0 = gr0[(size_t)(t - 1) * B + b];
            float r1 = gr1[(size_t)(t - 1) * B + b];
            step(x0, x1, r0, r1);
            __builtin_nontemporal_store(hx, &o0[(size_t)t * B + b]);
            __builtin_nontemporal_store(hy, &o1[(size_t)t * B + b]);
        }
    }

    // hT = last h, shape (2,1,B) appended after output
    __builtin_nontemporal_store(hx, out + 2 * TB + b);
    __builtin_nontemporal_store(hy, out + 2 * TB + B + b);
}

extern "C" void kernel_launch(void* const* d_in, const int* in_sizes, int n_in,
                              void* d_out, int out_size, void* d_ws, size_t ws_size,
                              hipStream_t stream) {
    const float* xin      = (const float*)d_in[0];
    const float* target   = (const float*)d_in[1];
    const float* rets     = (const float*)d_in[2];
    // d_in[3] = hidden (unused by reference)
    const float* w_input  = (const float*)d_in[4];
    const float* w_hidden = (const float*)d_in[5];
    const float* b_hidden = (const float*)d_in[6];
    const float* w_fc1    = (const float*)d_in[7];
    const float* w_fc2    = (const float*)d_in[8];
    const float* w_rotate = (const float*)d_in[9];
    float* out = (float*)d_out;

    const int B = in_sizes[3] / 2;             // hidden is (2,1,B)
    const int T = in_sizes[0] / in_sizes[3];   // input is (2,T,B)

    const int threads = 64;
    const int blocks  = (B + threads - 1) / threads;
    hipLaunchKernelGGL(ntr_rnn_kernel, dim3(blocks), dim3(threads), 0, stream,
                       xin, target, rets, w_input, w_hidden, b_hidden,
                       w_fc1, w_fc2, w_rotate, out, T, B);
}